// Round 1
// baseline (1101.578 us; speedup 1.0000x reference)
//
#include <hip/hip_runtime.h>

#define NNODES 100000
#define NEDGES 625000
#define DFEAT  128
#define NGRAPH 256
#define DOUTC  10

// ---------------------------------------------------------------------------
// CSR build: histogram -> scan -> scatter (counting sort of edges by row)
// ---------------------------------------------------------------------------
__global__ __launch_bounds__(256) void histo_kernel(const int* __restrict__ rows,
                                                    int* __restrict__ deg) {
    int i = blockIdx.x * 256 + threadIdx.x;
    if (i < NEDGES) atomicAdd(&deg[rows[i]], 1);
}

// 1024 elements per block (256 threads x 4)
__global__ __launch_bounds__(256) void scan_block_sums(const int* __restrict__ deg,
                                                       int* __restrict__ bsum) {
    __shared__ int red[256];
    int b = blockIdx.x, t = threadIdx.x;
    int base = b * 1024 + t * 4;
    int s = 0;
#pragma unroll
    for (int j = 0; j < 4; ++j) {
        int i = base + j;
        if (i < NNODES) s += deg[i];
    }
    red[t] = s;
    __syncthreads();
    for (int off = 128; off > 0; off >>= 1) {
        if (t < off) red[t] += red[t + off];
        __syncthreads();
    }
    if (t == 0) bsum[b] = red[0];
}

__global__ __launch_bounds__(128) void scan_bsum(const int* __restrict__ bsum,
                                                 int* __restrict__ bbase, int nb) {
    __shared__ int sh[128];
    int t = threadIdx.x;
    sh[t] = (t < nb) ? bsum[t] : 0;
    __syncthreads();
    if (t == 0) {
        int run = 0;
        for (int i = 0; i < nb; ++i) { int v = sh[i]; sh[i] = run; run += v; }
    }
    __syncthreads();
    if (t < nb) bbase[t] = sh[t];
}

__global__ __launch_bounds__(256) void scan_write(const int* __restrict__ deg,
                                                  const int* __restrict__ bbase,
                                                  int* __restrict__ offs,
                                                  int* __restrict__ cursor) {
    __shared__ int red[256];
    int b = blockIdx.x, t = threadIdx.x;
    int base = b * 1024 + t * 4;
    int v[4];
    int s = 0;
#pragma unroll
    for (int j = 0; j < 4; ++j) {
        int i = base + j;
        v[j] = (i < NNODES) ? deg[i] : 0;
        s += v[j];
    }
    red[t] = s;
    __syncthreads();
    // inclusive Hillis-Steele scan over 256 thread sums
    int x = s;
    for (int off = 1; off < 256; off <<= 1) {
        int y = (t >= off) ? red[t - off] : 0;
        __syncthreads();
        x += y;
        red[t] = x;
        __syncthreads();
    }
    int pre = bbase[b] + x - s;   // exclusive prefix for this thread's 4 items
#pragma unroll
    for (int j = 0; j < 4; ++j) {
        int i = base + j;
        if (i < NNODES) { offs[i] = pre; cursor[i] = pre; }
        pre += v[j];
    }
    if (b == gridDim.x - 1 && t == 255) offs[NNODES] = bbase[b] + x;  // == NEDGES
}

__global__ __launch_bounds__(256) void scatter_edges(const int* __restrict__ rows,
                                                     const int* __restrict__ cols,
                                                     int* __restrict__ cursor,
                                                     int* __restrict__ scol) {
    int i = blockIdx.x * 256 + threadIdx.x;
    if (i < NEDGES) {
        int p = atomicAdd(&cursor[rows[i]], 1);
        scol[p] = cols[i];
    }
}

// ---------------------------------------------------------------------------
// Fused dual GEMM: S = H @ W1^T, Y = H @ W2^T   (H:[N,128], W:[128,128] [out,in])
// Block: 256 threads, 64 rows. Thread: 8 rows x 4 cols x 2 outputs (64 acc).
// ---------------------------------------------------------------------------
__global__ __launch_bounds__(256) void dual_gemm(const float* __restrict__ Hin,
                                                 const float* __restrict__ W1,
                                                 const float* __restrict__ W2,
                                                 float* __restrict__ S,
                                                 float* __restrict__ Yout) {
    __shared__ float xs[64][DFEAT];
    int tid = threadIdx.x;
    int rowBase = blockIdx.x * 64;

    // stage 64x128 f32 tile (32 KiB) via float4
#pragma unroll
    for (int i = 0; i < 8; ++i) {
        int idx = tid + i * 256;        // float4 index in [0, 2048)
        int r = idx >> 5;               // 32 float4 per row
        int k4 = (idx & 31) << 2;
        int gr = rowBase + r;
        float4 v = make_float4(0.f, 0.f, 0.f, 0.f);
        if (gr < NNODES) v = *(const float4*)&Hin[(size_t)gr * DFEAT + k4];
        *(float4*)&xs[r][k4] = v;
    }
    __syncthreads();

    int c0 = (tid & 31) * 4;
    int rb = (tid >> 5) * 8;
    float acc_s[8][4] = {};
    float acc_y[8][4] = {};

    for (int kk = 0; kk < DFEAT; kk += 4) {
        float4 w1v[4], w2v[4];
#pragma unroll
        for (int c = 0; c < 4; ++c) {
            w1v[c] = *(const float4*)&W1[(c0 + c) * DFEAT + kk];
            w2v[c] = *(const float4*)&W2[(c0 + c) * DFEAT + kk];
        }
#pragma unroll
        for (int r = 0; r < 8; ++r) {
            float4 xv = *(const float4*)&xs[rb + r][kk];
#pragma unroll
            for (int c = 0; c < 4; ++c) {
                acc_s[r][c] += xv.x * w1v[c].x + xv.y * w1v[c].y +
                               xv.z * w1v[c].z + xv.w * w1v[c].w;
                acc_y[r][c] += xv.x * w2v[c].x + xv.y * w2v[c].y +
                               xv.z * w2v[c].z + xv.w * w2v[c].w;
            }
        }
    }

#pragma unroll
    for (int r = 0; r < 8; ++r) {
        int gr = rowBase + rb + r;
        if (gr < NNODES) {
            *(float4*)&S[(size_t)gr * DFEAT + c0] =
                make_float4(acc_s[r][0], acc_s[r][1], acc_s[r][2], acc_s[r][3]);
            *(float4*)&Yout[(size_t)gr * DFEAT + c0] =
                make_float4(acc_y[r][0], acc_y[r][1], acc_y[r][2], acc_y[r][3]);
        }
    }
}

// ---------------------------------------------------------------------------
// Aggregate + ReLU: H[n] = relu(S[n] + sum_{e in CSR[n]} Y[scol[e]])
// One wave (64 lanes) per node; each lane owns 2 features (float2).
// ---------------------------------------------------------------------------
__global__ __launch_bounds__(256) void aggregate_relu(const float* __restrict__ S,
                                                      const float* __restrict__ Y,
                                                      const int* __restrict__ offs,
                                                      const int* __restrict__ scol,
                                                      float* __restrict__ Hout) {
    int wave = (blockIdx.x * 256 + threadIdx.x) >> 6;
    int lane = threadIdx.x & 63;
    if (wave >= NNODES) return;
    int beg = offs[wave];
    int end = offs[wave + 1];
    float ax = 0.f, ay = 0.f;
    for (int e = beg; e < end; ++e) {
        int c = scol[e];
        float2 v = *(const float2*)&Y[(size_t)c * DFEAT + lane * 2];
        ax += v.x;
        ay += v.y;
    }
    float2 s = *(const float2*)&S[(size_t)wave * DFEAT + lane * 2];
    float2 h;
    h.x = fmaxf(s.x + ax, 0.f);
    h.y = fmaxf(s.y + ay, 0.f);
    *(float2*)&Hout[(size_t)wave * DFEAT + lane * 2] = h;
}

// ---------------------------------------------------------------------------
// Per-graph mean pool + classifier. Block g (128 threads): binary-search the
// sorted batch array for [beg,end), column-sum H, then out[g] = pooled@Wc^T+bc.
// ---------------------------------------------------------------------------
__global__ __launch_bounds__(128) void pool_classify(const float* __restrict__ H,
                                                     const int* __restrict__ batch,
                                                     const float* __restrict__ Wc,
                                                     const float* __restrict__ bc,
                                                     float* __restrict__ out) {
    int g = blockIdx.x;
    int f = threadIdx.x;
    __shared__ int bounds[2];
    if (f < 2) {
        int target = g + f;   // lower_bound(batch, target)
        int lo = 0, hi = NNODES;
        while (lo < hi) {
            int mid = (lo + hi) >> 1;
            if (batch[mid] < target) lo = mid + 1; else hi = mid;
        }
        bounds[f] = lo;
    }
    __syncthreads();
    int beg = bounds[0], end = bounds[1];
    float sum = 0.f;
    for (int n = beg; n < end; ++n) sum += H[(size_t)n * DFEAT + f];
    float cnt = (float)(end - beg);
    float pooled = sum / fmaxf(cnt, 1.0f);

    __shared__ float red[128];
    for (int o = 0; o < DOUTC; ++o) {
        red[f] = pooled * Wc[o * DFEAT + f];
        __syncthreads();
        for (int off = 64; off > 0; off >>= 1) {
            if (f < off) red[f] += red[f + off];
            __syncthreads();
        }
        if (f == 0) out[g * DOUTC + o] = red[0] + bc[o];
        __syncthreads();
    }
}

// ---------------------------------------------------------------------------
extern "C" void kernel_launch(void* const* d_in, const int* in_sizes, int n_in,
                              void* d_out, int out_size, void* d_ws, size_t ws_size,
                              hipStream_t stream) {
    const float* x    = (const float*)d_in[0];
    const int*   ei   = (const int*)d_in[1];   // [2, E]
    const int*   batch= (const int*)d_in[2];
    const float* W1_0 = (const float*)d_in[3];
    const float* W2_0 = (const float*)d_in[4];
    const float* W1_1 = (const float*)d_in[5];
    const float* W2_1 = (const float*)d_in[6];
    const float* W1_2 = (const float*)d_in[7];
    const float* W2_2 = (const float*)d_in[8];
    const float* Wc   = (const float*)d_in[9];
    const float* bc   = (const float*)d_in[10];
    float* out = (float*)d_out;

    const int* rows = ei;            // edge_index[0] = segment (dst)
    const int* cols = ei + NEDGES;   // edge_index[1] = gather (src)

    // workspace carve-up (~157 MB)
    char* ws = (char*)d_ws;
    float* S = (float*)ws;              ws += (size_t)NNODES * DFEAT * sizeof(float);
    float* Y = (float*)ws;              ws += (size_t)NNODES * DFEAT * sizeof(float);
    float* H = (float*)ws;              ws += (size_t)NNODES * DFEAT * sizeof(float);
    int* deg    = (int*)ws;             ws += (size_t)NNODES * sizeof(int);
    int* offs   = (int*)ws;             ws += (size_t)(NNODES + 1) * sizeof(int);
    int* cursor = (int*)ws;             ws += (size_t)NNODES * sizeof(int);
    int* scol   = (int*)ws;             ws += (size_t)NEDGES * sizeof(int);
    int* bsum   = (int*)ws;             ws += 128 * sizeof(int);
    int* bbase  = (int*)ws;             ws += 128 * sizeof(int);

    const int NB = (NNODES + 1023) / 1024;   // 98

    // --- build CSR (edges constant across layers; rebuilt every call) ---
    hipMemsetAsync(deg, 0, (size_t)NNODES * sizeof(int), stream);
    histo_kernel<<<(NEDGES + 255) / 256, 256, 0, stream>>>(rows, deg);
    scan_block_sums<<<NB, 256, 0, stream>>>(deg, bsum);
    scan_bsum<<<1, 128, 0, stream>>>(bsum, bbase, NB);
    scan_write<<<NB, 256, 0, stream>>>(deg, bbase, offs, cursor);
    scatter_edges<<<(NEDGES + 255) / 256, 256, 0, stream>>>(rows, cols, cursor, scol);

    // --- 3 GNN layers ---
    const float* Ws1[3] = {W1_0, W1_1, W1_2};
    const float* Ws2[3] = {W2_0, W2_1, W2_2};
    const float* hin = x;
    const int gemmGrid = (NNODES + 63) / 64;
    const int aggGrid  = (NNODES * 64 + 255) / 256;
    for (int l = 0; l < 3; ++l) {
        dual_gemm<<<gemmGrid, 256, 0, stream>>>(hin, Ws1[l], Ws2[l], S, Y);
        aggregate_relu<<<aggGrid, 256, 0, stream>>>(S, Y, offs, scol, H);
        hin = H;
    }

    // --- pool + classify ---
    pool_classify<<<NGRAPH, 128, 0, stream>>>(H, batch, Wc, bc, out);
}

// Round 2
// 505.855 us; speedup vs baseline: 2.1777x; 2.1777x over previous
//
#include <hip/hip_runtime.h>

#define NNODES 100000
#define NEDGES 625000
#define DFEAT  128
#define NGRAPH 256
#define DOUTC  10

typedef __attribute__((ext_vector_type(8))) short bf16x8;
typedef __attribute__((ext_vector_type(4))) float f32x4;
typedef __attribute__((ext_vector_type(8))) ushort ushort8v;

__device__ __forceinline__ ushort f2bf(float f) {
    __bf16 b = (__bf16)f;                       // RNE, compiler can fuse to v_cvt_pk_bf16_f32
    return __builtin_bit_cast(ushort, b);
}
__device__ __forceinline__ float bf2f(ushort u) {
    return __builtin_bit_cast(float, (uint)u << 16);
}
__device__ __forceinline__ float bfhi2f(uint v) {   // high bf16 of a packed pair
    return __builtin_bit_cast(float, v & 0xffff0000u);
}
__device__ __forceinline__ float bflo2f(uint v) {   // low bf16 of a packed pair
    return __builtin_bit_cast(float, v << 16);
}

// ---------------------------------------------------------------------------
// CSR build: histogram -> scan -> scatter (counting sort of edges by row)
// ---------------------------------------------------------------------------
__global__ __launch_bounds__(256) void histo_kernel(const int* __restrict__ rows,
                                                    int* __restrict__ deg) {
    int i = blockIdx.x * 256 + threadIdx.x;
    if (i < NEDGES) atomicAdd(&deg[rows[i]], 1);
}

__global__ __launch_bounds__(256) void scan_block_sums(const int* __restrict__ deg,
                                                       int* __restrict__ bsum) {
    __shared__ int red[256];
    int b = blockIdx.x, t = threadIdx.x;
    int base = b * 1024 + t * 4;
    int s = 0;
#pragma unroll
    for (int j = 0; j < 4; ++j) {
        int i = base + j;
        if (i < NNODES) s += deg[i];
    }
    red[t] = s;
    __syncthreads();
    for (int off = 128; off > 0; off >>= 1) {
        if (t < off) red[t] += red[t + off];
        __syncthreads();
    }
    if (t == 0) bsum[b] = red[0];
}

__global__ __launch_bounds__(128) void scan_bsum(const int* __restrict__ bsum,
                                                 int* __restrict__ bbase, int nb) {
    __shared__ int sh[128];
    int t = threadIdx.x;
    sh[t] = (t < nb) ? bsum[t] : 0;
    __syncthreads();
    if (t == 0) {
        int run = 0;
        for (int i = 0; i < nb; ++i) { int v = sh[i]; sh[i] = run; run += v; }
    }
    __syncthreads();
    if (t < nb) bbase[t] = sh[t];
}

__global__ __launch_bounds__(256) void scan_write(const int* __restrict__ deg,
                                                  const int* __restrict__ bbase,
                                                  int* __restrict__ offs,
                                                  int* __restrict__ cursor) {
    __shared__ int red[256];
    int b = blockIdx.x, t = threadIdx.x;
    int base = b * 1024 + t * 4;
    int v[4];
    int s = 0;
#pragma unroll
    for (int j = 0; j < 4; ++j) {
        int i = base + j;
        v[j] = (i < NNODES) ? deg[i] : 0;
        s += v[j];
    }
    red[t] = s;
    __syncthreads();
    int x = s;
    for (int off = 1; off < 256; off <<= 1) {
        int y = (t >= off) ? red[t - off] : 0;
        __syncthreads();
        x += y;
        red[t] = x;
        __syncthreads();
    }
    int pre = bbase[b] + x - s;
#pragma unroll
    for (int j = 0; j < 4; ++j) {
        int i = base + j;
        if (i < NNODES) { offs[i] = pre; cursor[i] = pre; }
        pre += v[j];
    }
    if (b == gridDim.x - 1 && t == 255) offs[NNODES] = bbase[b] + x;
}

__global__ __launch_bounds__(256) void scatter_edges(const int* __restrict__ rows,
                                                     const int* __restrict__ cols,
                                                     int* __restrict__ cursor,
                                                     int* __restrict__ scol) {
    int i = blockIdx.x * 256 + threadIdx.x;
    if (i < NEDGES) {
        int p = atomicAdd(&cursor[rows[i]], 1);
        scol[p] = cols[i];
    }
}

// ---------------------------------------------------------------------------
// dtype conversion
// ---------------------------------------------------------------------------
__global__ __launch_bounds__(256) void convert_x_bf16(const float* __restrict__ src,
                                                      ushort* __restrict__ dst) {
    int i = blockIdx.x * 256 + threadIdx.x;            // 8 floats per thread
    const int n8 = NNODES * DFEAT / 8;
    if (i >= n8) return;
    float4 a = *(const float4*)&src[(size_t)i * 8];
    float4 b = *(const float4*)&src[(size_t)i * 8 + 4];
    ushort8v o;
    o[0] = f2bf(a.x); o[1] = f2bf(a.y); o[2] = f2bf(a.z); o[3] = f2bf(a.w);
    o[4] = f2bf(b.x); o[5] = f2bf(b.y); o[6] = f2bf(b.z); o[7] = f2bf(b.w);
    *(ushort8v*)&dst[(size_t)i * 8] = o;
}

__global__ __launch_bounds__(256) void convert_weights(const float* __restrict__ w0,
                                                       const float* __restrict__ w1,
                                                       const float* __restrict__ w2,
                                                       const float* __restrict__ w3,
                                                       const float* __restrict__ w4,
                                                       const float* __restrict__ w5,
                                                       ushort* __restrict__ dst) {
    int i = blockIdx.x * 256 + threadIdx.x;            // 6 * 16384 elems
    if (i >= 6 * DFEAT * DFEAT) return;
    const float* ptrs[6] = {w0, w1, w2, w3, w4, w5};
    int m = i >> 14, j = i & 16383;
    dst[i] = f2bf(ptrs[m][j]);
}

// ---------------------------------------------------------------------------
// Dual GEMM via bf16 MFMA: S = H @ W1^T, Y = H @ W2^T  (all [*,128], W [out,in])
// A-operand = W tile (M=16 out-rows), B-operand = H^T (N=16 nodes).
// Wave: 32 nodes (2 node-tiles) x 128 outs x 2 mats = 128 MFMAs.
// ---------------------------------------------------------------------------
__global__ __launch_bounds__(256) void dual_gemm_mfma(const ushort* __restrict__ Hb,
                                                      const ushort* __restrict__ W1b,
                                                      const ushort* __restrict__ W2b,
                                                      ushort* __restrict__ Sb,
                                                      ushort* __restrict__ Yb) {
    int wave = threadIdx.x >> 6;
    int lane = threadIdx.x & 63;
    int nodeBase = (blockIdx.x * 4 + wave) * 32;
    if (nodeBase >= NNODES) return;
    int l15 = lane & 15;
    int lhi = lane >> 4;                    // 0..3

    f32x4 acc[2][8][2] = {};                // [node-tile][out-tile][mat]

#pragma unroll
    for (int ks = 0; ks < 4; ++ks) {
        int k0 = ks * 32 + lhi * 8;
        bf16x8 hfrag[2];
#pragma unroll
        for (int nt = 0; nt < 2; ++nt) {
            size_t node = nodeBase + nt * 16 + l15;
            hfrag[nt] = *(const bf16x8*)&Hb[node * DFEAT + k0];
        }
#pragma unroll
        for (int ot = 0; ot < 8; ++ot) {
            int orow = ot * 16 + l15;
            bf16x8 w1 = *(const bf16x8*)&W1b[orow * DFEAT + k0];
            bf16x8 w2 = *(const bf16x8*)&W2b[orow * DFEAT + k0];
#pragma unroll
            for (int nt = 0; nt < 2; ++nt) {
                acc[nt][ot][0] = __builtin_amdgcn_mfma_f32_16x16x32_bf16(
                    w1, hfrag[nt], acc[nt][ot][0], 0, 0, 0);
                acc[nt][ot][1] = __builtin_amdgcn_mfma_f32_16x16x32_bf16(
                    w2, hfrag[nt], acc[nt][ot][1], 0, 0, 0);
            }
        }
    }

    // D: col(lane&15)=node, row((lane>>4)*4+reg)=out-feature -> 4 consecutive outs
#pragma unroll
    for (int nt = 0; nt < 2; ++nt) {
        size_t rowOff = (size_t)(nodeBase + nt * 16 + l15) * DFEAT;
#pragma unroll
        for (int ot = 0; ot < 8; ++ot) {
            int o = ot * 16 + lhi * 4;
            f32x4 a0 = acc[nt][ot][0];
            f32x4 a1 = acc[nt][ot][1];
            ushort4 p0, p1;
            p0.x = f2bf(a0.x); p0.y = f2bf(a0.y); p0.z = f2bf(a0.z); p0.w = f2bf(a0.w);
            p1.x = f2bf(a1.x); p1.y = f2bf(a1.y); p1.z = f2bf(a1.z); p1.w = f2bf(a1.w);
            *(ushort4*)&Sb[rowOff + o] = p0;
            *(ushort4*)&Yb[rowOff + o] = p1;
        }
    }
}

// ---------------------------------------------------------------------------
// Aggregate + ReLU (bf16 in/out, f32 accumulate)
// One wave per node; lane owns 2 features (one packed uint).
// ---------------------------------------------------------------------------
__global__ __launch_bounds__(256) void aggregate_relu_bf16(const ushort* __restrict__ Sb,
                                                           const ushort* __restrict__ Yb,
                                                           const int* __restrict__ offs,
                                                           const int* __restrict__ scol,
                                                           ushort* __restrict__ Hout) {
    int node = (blockIdx.x * 256 + threadIdx.x) >> 6;
    int lane = threadIdx.x & 63;
    if (node >= NNODES) return;
    int beg = offs[node];
    int end = offs[node + 1];
    const uint* Yp = (const uint*)Yb + lane;           // packed pair at feature 2*lane
    float ax = 0.f, ay = 0.f;
    int e = beg;
    for (; e + 1 < end; e += 2) {
        int c0 = scol[e];
        int c1 = scol[e + 1];
        uint v0 = Yp[(size_t)c0 * 64];
        uint v1 = Yp[(size_t)c1 * 64];
        ax += bflo2f(v0) + bflo2f(v1);
        ay += bfhi2f(v0) + bfhi2f(v1);
    }
    if (e < end) {
        uint v0 = Yp[(size_t)scol[e] * 64];
        ax += bflo2f(v0);
        ay += bfhi2f(v0);
    }
    uint sv = ((const uint*)Sb)[(size_t)node * 64 + lane];
    float hx = fmaxf(bflo2f(sv) + ax, 0.f);
    float hy = fmaxf(bfhi2f(sv) + ay, 0.f);
    uint packed = (uint)f2bf(hx) | ((uint)f2bf(hy) << 16);
    ((uint*)Hout)[(size_t)node * 64 + lane] = packed;
}

// ---------------------------------------------------------------------------
// Per-graph mean pool (bf16 H) + f32 classifier
// ---------------------------------------------------------------------------
__global__ __launch_bounds__(128) void pool_classify(const ushort* __restrict__ Hb,
                                                     const int* __restrict__ batch,
                                                     const float* __restrict__ Wc,
                                                     const float* __restrict__ bc,
                                                     float* __restrict__ out) {
    int g = blockIdx.x;
    int f = threadIdx.x;
    __shared__ int bounds[2];
    if (f < 2) {
        int target = g + f;
        int lo = 0, hi = NNODES;
        while (lo < hi) {
            int mid = (lo + hi) >> 1;
            if (batch[mid] < target) lo = mid + 1; else hi = mid;
        }
        bounds[f] = lo;
    }
    __syncthreads();
    int beg = bounds[0], end = bounds[1];
    float sum = 0.f;
    for (int n = beg; n < end; ++n) sum += bf2f(Hb[(size_t)n * DFEAT + f]);
    float cnt = (float)(end - beg);
    float pooled = sum / fmaxf(cnt, 1.0f);

    __shared__ float red[128];
    for (int o = 0; o < DOUTC; ++o) {
        red[f] = pooled * Wc[o * DFEAT + f];
        __syncthreads();
        for (int off = 64; off > 0; off >>= 1) {
            if (f < off) red[f] += red[f + off];
            __syncthreads();
        }
        if (f == 0) out[g * DOUTC + o] = red[0] + bc[o];
        __syncthreads();
    }
}

// ---------------------------------------------------------------------------
extern "C" void kernel_launch(void* const* d_in, const int* in_sizes, int n_in,
                              void* d_out, int out_size, void* d_ws, size_t ws_size,
                              hipStream_t stream) {
    const float* x    = (const float*)d_in[0];
    const int*   ei   = (const int*)d_in[1];
    const int*   batch= (const int*)d_in[2];
    const float* W1_0 = (const float*)d_in[3];
    const float* W2_0 = (const float*)d_in[4];
    const float* W1_1 = (const float*)d_in[5];
    const float* W2_1 = (const float*)d_in[6];
    const float* W1_2 = (const float*)d_in[7];
    const float* W2_2 = (const float*)d_in[8];
    const float* Wc   = (const float*)d_in[9];
    const float* bc   = (const float*)d_in[10];
    float* out = (float*)d_out;

    const int* rows = ei;            // edge_index[0] = dst (segment)
    const int* cols = ei + NEDGES;   // edge_index[1] = src (gather)

    // workspace carve-up (~81 MB)
    char* ws = (char*)d_ws;
    ushort* Hb = (ushort*)ws;  ws += (size_t)NNODES * DFEAT * sizeof(ushort);
    ushort* Sb = (ushort*)ws;  ws += (size_t)NNODES * DFEAT * sizeof(ushort);
    ushort* Yb = (ushort*)ws;  ws += (size_t)NNODES * DFEAT * sizeof(ushort);
    ushort* Wb = (ushort*)ws;  ws += (size_t)6 * DFEAT * DFEAT * sizeof(ushort);
    int* deg    = (int*)ws;    ws += (size_t)NNODES * sizeof(int);
    int* offs   = (int*)ws;    ws += (size_t)(NNODES + 1) * sizeof(int);
    int* cursor = (int*)ws;    ws += (size_t)NNODES * sizeof(int);
    int* scol   = (int*)ws;    ws += (size_t)NEDGES * sizeof(int);
    int* bsum   = (int*)ws;    ws += 128 * sizeof(int);
    int* bbase  = (int*)ws;    ws += 128 * sizeof(int);

    const int NB = (NNODES + 1023) / 1024;

    // dtype conversion
    convert_weights<<<(6 * DFEAT * DFEAT + 255) / 256, 256, 0, stream>>>(
        W1_0, W2_0, W1_1, W2_1, W1_2, W2_2, Wb);
    convert_x_bf16<<<(NNODES * DFEAT / 8 + 255) / 256, 256, 0, stream>>>(x, Hb);

    // CSR build
    hipMemsetAsync(deg, 0, (size_t)NNODES * sizeof(int), stream);
    histo_kernel<<<(NEDGES + 255) / 256, 256, 0, stream>>>(rows, deg);
    scan_block_sums<<<NB, 256, 0, stream>>>(deg, bsum);
    scan_bsum<<<1, 128, 0, stream>>>(bsum, bbase, NB);
    scan_write<<<NB, 256, 0, stream>>>(deg, bbase, offs, cursor);
    scatter_edges<<<(NEDGES + 255) / 256, 256, 0, stream>>>(rows, cols, cursor, scol);

    // 3 GNN layers (Hb is both input and output of each layer)
    const int gemmGrid = ((NNODES / 32) + 3) / 4;              // 782 blocks, wave=32 nodes
    const int aggGrid  = ((size_t)NNODES * 64 + 255) / 256;
    for (int l = 0; l < 3; ++l) {
        const ushort* w1 = Wb + (size_t)(2 * l) * DFEAT * DFEAT;
        const ushort* w2 = Wb + (size_t)(2 * l + 1) * DFEAT * DFEAT;
        dual_gemm_mfma<<<gemmGrid, 256, 0, stream>>>(Hb, w1, w2, Sb, Yb);
        aggregate_relu_bf16<<<aggGrid, 256, 0, stream>>>(Sb, Yb, offs, scol, Hb);
    }

    pool_classify<<<NGRAPH, 128, 0, stream>>>(Hb, batch, Wc, bc, out);
}

// Round 3
// 411.670 us; speedup vs baseline: 2.6759x; 1.2288x over previous
//
#include <hip/hip_runtime.h>

#define NNODES 100000
#define NEDGES 625000
#define DFEAT  128
#define NGRAPH 256
#define DOUTC  10

typedef __attribute__((ext_vector_type(8))) short bf16x8;
typedef __attribute__((ext_vector_type(4))) float f32x4;
typedef __attribute__((ext_vector_type(8))) ushort ushort8v;

__device__ __forceinline__ ushort f2bf(float f) {
    __bf16 b = (__bf16)f;
    return __builtin_bit_cast(ushort, b);
}
__device__ __forceinline__ float bf2f(ushort u) {
    return __builtin_bit_cast(float, (uint)u << 16);
}
__device__ __forceinline__ float bfhi2f(uint v) {
    return __builtin_bit_cast(float, v & 0xffff0000u);
}
__device__ __forceinline__ float bflo2f(uint v) {
    return __builtin_bit_cast(float, v << 16);
}

// ---------------------------------------------------------------------------
// CSR build: histogram -> scan -> scatter (counting sort of edges by row)
// ---------------------------------------------------------------------------
__global__ __launch_bounds__(256) void histo_kernel(const int* __restrict__ rows,
                                                    int* __restrict__ deg) {
    int i = blockIdx.x * 256 + threadIdx.x;
    if (i < NEDGES) atomicAdd(&deg[rows[i]], 1);
}

__global__ __launch_bounds__(256) void scan_block_sums(const int* __restrict__ deg,
                                                       int* __restrict__ bsum) {
    __shared__ int red[256];
    int b = blockIdx.x, t = threadIdx.x;
    int base = b * 1024 + t * 4;
    int s = 0;
#pragma unroll
    for (int j = 0; j < 4; ++j) {
        int i = base + j;
        if (i < NNODES) s += deg[i];
    }
    red[t] = s;
    __syncthreads();
    for (int off = 128; off > 0; off >>= 1) {
        if (t < off) red[t] += red[t + off];
        __syncthreads();
    }
    if (t == 0) bsum[b] = red[0];
}

__global__ __launch_bounds__(128) void scan_bsum(const int* __restrict__ bsum,
                                                 int* __restrict__ bbase, int nb) {
    __shared__ int sh[128];
    int t = threadIdx.x;
    sh[t] = (t < nb) ? bsum[t] : 0;
    __syncthreads();
    if (t == 0) {
        int run = 0;
        for (int i = 0; i < nb; ++i) { int v = sh[i]; sh[i] = run; run += v; }
    }
    __syncthreads();
    if (t < nb) bbase[t] = sh[t];
}

__global__ __launch_bounds__(256) void scan_write(const int* __restrict__ deg,
                                                  const int* __restrict__ bbase,
                                                  int* __restrict__ offs,
                                                  int* __restrict__ cursor) {
    __shared__ int red[256];
    int b = blockIdx.x, t = threadIdx.x;
    int base = b * 1024 + t * 4;
    int v[4];
    int s = 0;
#pragma unroll
    for (int j = 0; j < 4; ++j) {
        int i = base + j;
        v[j] = (i < NNODES) ? deg[i] : 0;
        s += v[j];
    }
    red[t] = s;
    __syncthreads();
    int x = s;
    for (int off = 1; off < 256; off <<= 1) {
        int y = (t >= off) ? red[t - off] : 0;
        __syncthreads();
        x += y;
        red[t] = x;
        __syncthreads();
    }
    int pre = bbase[b] + x - s;
#pragma unroll
    for (int j = 0; j < 4; ++j) {
        int i = base + j;
        if (i < NNODES) { offs[i] = pre; cursor[i] = pre; }
        pre += v[j];
    }
    if (b == gridDim.x - 1 && t == 255) offs[NNODES] = bbase[b] + x;
}

__global__ __launch_bounds__(256) void scatter_edges(const int* __restrict__ rows,
                                                     const int* __restrict__ cols,
                                                     int* __restrict__ cursor,
                                                     int* __restrict__ scol) {
    int i = blockIdx.x * 256 + threadIdx.x;
    if (i < NEDGES) {
        int p = atomicAdd(&cursor[rows[i]], 1);
        scol[p] = cols[i];
    }
}

// ---------------------------------------------------------------------------
// dtype conversion
// ---------------------------------------------------------------------------
__global__ __launch_bounds__(256) void convert_x_bf16(const float* __restrict__ src,
                                                      ushort* __restrict__ dst) {
    int i = blockIdx.x * 256 + threadIdx.x;
    const int n8 = NNODES * DFEAT / 8;
    if (i >= n8) return;
    float4 a = *(const float4*)&src[(size_t)i * 8];
    float4 b = *(const float4*)&src[(size_t)i * 8 + 4];
    ushort8v o;
    o[0] = f2bf(a.x); o[1] = f2bf(a.y); o[2] = f2bf(a.z); o[3] = f2bf(a.w);
    o[4] = f2bf(b.x); o[5] = f2bf(b.y); o[6] = f2bf(b.z); o[7] = f2bf(b.w);
    *(ushort8v*)&dst[(size_t)i * 8] = o;
}

__global__ __launch_bounds__(256) void convert_weights(const float* __restrict__ w0,
                                                       const float* __restrict__ w1,
                                                       const float* __restrict__ w2,
                                                       const float* __restrict__ w3,
                                                       const float* __restrict__ w4,
                                                       const float* __restrict__ w5,
                                                       ushort* __restrict__ dst) {
    int i = blockIdx.x * 256 + threadIdx.x;
    if (i >= 6 * DFEAT * DFEAT) return;
    const float* ptrs[6] = {w0, w1, w2, w3, w4, w5};
    int m = i >> 14, j = i & 16383;
    dst[i] = f2bf(ptrs[m][j]);
}

// ---------------------------------------------------------------------------
// Dual GEMM via bf16 MFMA: S = H @ W1^T, Y = H @ W2^T
// ---------------------------------------------------------------------------
__global__ __launch_bounds__(256) void dual_gemm_mfma(const ushort* __restrict__ Hb,
                                                      const ushort* __restrict__ W1b,
                                                      const ushort* __restrict__ W2b,
                                                      ushort* __restrict__ Sb,
                                                      ushort* __restrict__ Yb) {
    int wave = threadIdx.x >> 6;
    int lane = threadIdx.x & 63;
    int nodeBase = (blockIdx.x * 4 + wave) * 32;
    if (nodeBase >= NNODES) return;
    int l15 = lane & 15;
    int lhi = lane >> 4;

    f32x4 acc[2][8][2] = {};

#pragma unroll
    for (int ks = 0; ks < 4; ++ks) {
        int k0 = ks * 32 + lhi * 8;
        bf16x8 hfrag[2];
#pragma unroll
        for (int nt = 0; nt < 2; ++nt) {
            size_t node = nodeBase + nt * 16 + l15;
            hfrag[nt] = *(const bf16x8*)&Hb[node * DFEAT + k0];
        }
#pragma unroll
        for (int ot = 0; ot < 8; ++ot) {
            int orow = ot * 16 + l15;
            bf16x8 w1 = *(const bf16x8*)&W1b[orow * DFEAT + k0];
            bf16x8 w2 = *(const bf16x8*)&W2b[orow * DFEAT + k0];
#pragma unroll
            for (int nt = 0; nt < 2; ++nt) {
                acc[nt][ot][0] = __builtin_amdgcn_mfma_f32_16x16x32_bf16(
                    w1, hfrag[nt], acc[nt][ot][0], 0, 0, 0);
                acc[nt][ot][1] = __builtin_amdgcn_mfma_f32_16x16x32_bf16(
                    w2, hfrag[nt], acc[nt][ot][1], 0, 0, 0);
            }
        }
    }

#pragma unroll
    for (int nt = 0; nt < 2; ++nt) {
        size_t rowOff = (size_t)(nodeBase + nt * 16 + l15) * DFEAT;
#pragma unroll
        for (int ot = 0; ot < 8; ++ot) {
            int o = ot * 16 + lhi * 4;
            f32x4 a0 = acc[nt][ot][0];
            f32x4 a1 = acc[nt][ot][1];
            ushort4 p0, p1;
            p0.x = f2bf(a0.x); p0.y = f2bf(a0.y); p0.z = f2bf(a0.z); p0.w = f2bf(a0.w);
            p1.x = f2bf(a1.x); p1.y = f2bf(a1.y); p1.z = f2bf(a1.z); p1.w = f2bf(a1.w);
            *(ushort4*)&Sb[rowOff + o] = p0;
            *(ushort4*)&Yb[rowOff + o] = p1;
        }
    }
}

// ---------------------------------------------------------------------------
// Aggregate + ReLU (bf16 in/out, f32 accumulate). One wave per node.
// ---------------------------------------------------------------------------
__global__ __launch_bounds__(256) void aggregate_relu_bf16(const ushort* __restrict__ Sb,
                                                           const ushort* __restrict__ Yb,
                                                           const int* __restrict__ offs,
                                                           const int* __restrict__ scol,
                                                           ushort* __restrict__ Hout) {
    int node = (blockIdx.x * 256 + threadIdx.x) >> 6;
    int lane = threadIdx.x & 63;
    if (node >= NNODES) return;
    int beg = offs[node];
    int end = offs[node + 1];
    const uint* Yp = (const uint*)Yb + lane;
    float ax = 0.f, ay = 0.f;
    int e = beg;
    for (; e + 3 < end; e += 4) {
        int c0 = scol[e], c1 = scol[e + 1], c2 = scol[e + 2], c3 = scol[e + 3];
        uint v0 = Yp[(size_t)c0 * 64];
        uint v1 = Yp[(size_t)c1 * 64];
        uint v2 = Yp[(size_t)c2 * 64];
        uint v3 = Yp[(size_t)c3 * 64];
        ax += (bflo2f(v0) + bflo2f(v1)) + (bflo2f(v2) + bflo2f(v3));
        ay += (bfhi2f(v0) + bfhi2f(v1)) + (bfhi2f(v2) + bfhi2f(v3));
    }
    for (; e < end; ++e) {
        uint v0 = Yp[(size_t)scol[e] * 64];
        ax += bflo2f(v0);
        ay += bfhi2f(v0);
    }
    uint sv = ((const uint*)Sb)[(size_t)node * 64 + lane];
    float hx = fmaxf(bflo2f(sv) + ax, 0.f);
    float hy = fmaxf(bfhi2f(sv) + ay, 0.f);
    uint packed = (uint)f2bf(hx) | ((uint)f2bf(hy) << 16);
    ((uint*)Hout)[(size_t)node * 64 + lane] = packed;
}

// ---------------------------------------------------------------------------
// Pooling phase 1: per-graph feature sums. One wave per 64-node contiguous
// chunk; lane owns 2 packed features; run-accumulate (batch sorted) + atomic
// flush at graph boundaries.
// ---------------------------------------------------------------------------
__global__ __launch_bounds__(256) void pool_partial(const ushort* __restrict__ Hb,
                                                    const int* __restrict__ batch,
                                                    float* __restrict__ gsum) {
    int wave = (blockIdx.x * 256 + threadIdx.x) >> 6;
    int lane = threadIdx.x & 63;
    int base = wave * 64;
    if (base >= NNODES) return;
    int end = min(base + 64, NNODES);
    const uint* Hp = (const uint*)Hb + lane;
    float ax = 0.f, ay = 0.f;
    int gprev = batch[base];
    for (int n = base; n < end; ++n) {
        int g = batch[n];                       // wave-uniform
        if (g != gprev) {
            atomicAdd(&gsum[gprev * DFEAT + lane * 2], ax);
            atomicAdd(&gsum[gprev * DFEAT + lane * 2 + 1], ay);
            ax = 0.f; ay = 0.f; gprev = g;
        }
        uint v = Hp[(size_t)n * 64];
        ax += bflo2f(v);
        ay += bfhi2f(v);
    }
    atomicAdd(&gsum[gprev * DFEAT + lane * 2], ax);
    atomicAdd(&gsum[gprev * DFEAT + lane * 2 + 1], ay);
}

// ---------------------------------------------------------------------------
// Pooling phase 2: divide by count, classify. One block (128 thr) per graph.
// ---------------------------------------------------------------------------
__global__ __launch_bounds__(128) void pool_classify2(const float* __restrict__ gsum,
                                                      const int* __restrict__ batch,
                                                      const float* __restrict__ Wc,
                                                      const float* __restrict__ bc,
                                                      float* __restrict__ out) {
    int g = blockIdx.x;
    int f = threadIdx.x;
    __shared__ int bounds[2];
    if (f < 2) {
        int target = g + f;
        int lo = 0, hi = NNODES;
        while (lo < hi) {
            int mid = (lo + hi) >> 1;
            if (batch[mid] < target) lo = mid + 1; else hi = mid;
        }
        bounds[f] = lo;
    }
    __syncthreads();
    float cnt = (float)(bounds[1] - bounds[0]);
    float pooled = gsum[g * DFEAT + f] / fmaxf(cnt, 1.0f);

    __shared__ float red[128];
    for (int o = 0; o < DOUTC; ++o) {
        red[f] = pooled * Wc[o * DFEAT + f];
        __syncthreads();
        for (int off = 64; off > 0; off >>= 1) {
            if (f < off) red[f] += red[f + off];
            __syncthreads();
        }
        if (f == 0) out[g * DOUTC + o] = red[0] + bc[o];
        __syncthreads();
    }
}

// ---------------------------------------------------------------------------
extern "C" void kernel_launch(void* const* d_in, const int* in_sizes, int n_in,
                              void* d_out, int out_size, void* d_ws, size_t ws_size,
                              hipStream_t stream) {
    const float* x    = (const float*)d_in[0];
    const int*   ei   = (const int*)d_in[1];
    const int*   batch= (const int*)d_in[2];
    const float* W1_0 = (const float*)d_in[3];
    const float* W2_0 = (const float*)d_in[4];
    const float* W1_1 = (const float*)d_in[5];
    const float* W2_1 = (const float*)d_in[6];
    const float* W1_2 = (const float*)d_in[7];
    const float* W2_2 = (const float*)d_in[8];
    const float* Wc   = (const float*)d_in[9];
    const float* bc   = (const float*)d_in[10];
    float* out = (float*)d_out;

    const int* rows = ei;            // edge_index[0] = dst (segment)
    const int* cols = ei + NEDGES;   // edge_index[1] = src (gather)

    // workspace carve-up
    char* ws = (char*)d_ws;
    ushort* Hb = (ushort*)ws;  ws += (size_t)NNODES * DFEAT * sizeof(ushort);
    ushort* Sb = (ushort*)ws;  ws += (size_t)NNODES * DFEAT * sizeof(ushort);
    ushort* Yb = (ushort*)ws;  ws += (size_t)NNODES * DFEAT * sizeof(ushort);
    ushort* Wb = (ushort*)ws;  ws += (size_t)6 * DFEAT * DFEAT * sizeof(ushort);
    float* gsum = (float*)ws;  ws += (size_t)NGRAPH * DFEAT * sizeof(float);
    int* deg    = (int*)ws;    ws += (size_t)NNODES * sizeof(int);
    int* offs   = (int*)ws;    ws += (size_t)(NNODES + 1) * sizeof(int);
    int* cursor = (int*)ws;    ws += (size_t)NNODES * sizeof(int);
    int* scol   = (int*)ws;    ws += (size_t)NEDGES * sizeof(int);
    int* bsum   = (int*)ws;    ws += 128 * sizeof(int);
    int* bbase  = (int*)ws;    ws += 128 * sizeof(int);

    const int NB = (NNODES + 1023) / 1024;

    // dtype conversion
    convert_weights<<<(6 * DFEAT * DFEAT + 255) / 256, 256, 0, stream>>>(
        W1_0, W2_0, W1_1, W2_1, W1_2, W2_2, Wb);
    convert_x_bf16<<<(NNODES * DFEAT / 8 + 255) / 256, 256, 0, stream>>>(x, Hb);

    // CSR build
    hipMemsetAsync(deg, 0, (size_t)NNODES * sizeof(int), stream);
    hipMemsetAsync(gsum, 0, (size_t)NGRAPH * DFEAT * sizeof(float), stream);
    histo_kernel<<<(NEDGES + 255) / 256, 256, 0, stream>>>(rows, deg);
    scan_block_sums<<<NB, 256, 0, stream>>>(deg, bsum);
    scan_bsum<<<1, 128, 0, stream>>>(bsum, bbase, NB);
    scan_write<<<NB, 256, 0, stream>>>(deg, bbase, offs, cursor);
    scatter_edges<<<(NEDGES + 255) / 256, 256, 0, stream>>>(rows, cols, cursor, scol);

    // 3 GNN layers
    const int gemmGrid = ((NNODES / 32) + 3) / 4;
    const int aggGrid  = ((size_t)NNODES * 64 + 255) / 256;
    for (int l = 0; l < 3; ++l) {
        const ushort* w1 = Wb + (size_t)(2 * l) * DFEAT * DFEAT;
        const ushort* w2 = Wb + (size_t)(2 * l + 1) * DFEAT * DFEAT;
        dual_gemm_mfma<<<gemmGrid, 256, 0, stream>>>(Hb, w1, w2, Sb, Yb);
        aggregate_relu_bf16<<<aggGrid, 256, 0, stream>>>(Sb, Yb, offs, scol, Hb);
    }

    // pooling + classifier
    const int poolWaves = (NNODES + 63) / 64;                 // 1563
    pool_partial<<<(poolWaves * 64 + 255) / 256, 256, 0, stream>>>(Hb, batch, gsum);
    pool_classify2<<<NGRAPH, 128, 0, stream>>>(gsum, batch, Wc, bc, out);
}

// Round 4
// 370.455 us; speedup vs baseline: 2.9736x; 1.1113x over previous
//
#include <hip/hip_runtime.h>

#define NNODES 100000
#define NEDGES 625000
#define DFEAT  128
#define NGRAPH 256
#define DOUTC  10

typedef __attribute__((ext_vector_type(8))) short bf16x8;
typedef __attribute__((ext_vector_type(4))) float f32x4;
typedef __attribute__((ext_vector_type(8))) ushort ushort8v;

__device__ __forceinline__ ushort f2bf(float f) {
    __bf16 b = (__bf16)f;
    return __builtin_bit_cast(ushort, b);
}
__device__ __forceinline__ float bf2f(ushort u) {
    return __builtin_bit_cast(float, (uint)u << 16);
}
__device__ __forceinline__ float bfhi2f(uint v) {
    return __builtin_bit_cast(float, v & 0xffff0000u);
}
__device__ __forceinline__ float bflo2f(uint v) {
    return __builtin_bit_cast(float, v << 16);
}

// ---------------------------------------------------------------------------
// CSR build: histogram -> scan -> scatter (counting sort of edges by row)
// ---------------------------------------------------------------------------
__global__ __launch_bounds__(256) void histo_kernel(const int* __restrict__ rows,
                                                    int* __restrict__ deg) {
    int i = blockIdx.x * 256 + threadIdx.x;
    if (i < NEDGES) atomicAdd(&deg[rows[i]], 1);
}

__global__ __launch_bounds__(256) void scan_block_sums(const int* __restrict__ deg,
                                                       int* __restrict__ bsum) {
    __shared__ int red[256];
    int b = blockIdx.x, t = threadIdx.x;
    int base = b * 1024 + t * 4;
    int s = 0;
#pragma unroll
    for (int j = 0; j < 4; ++j) {
        int i = base + j;
        if (i < NNODES) s += deg[i];
    }
    red[t] = s;
    __syncthreads();
    for (int off = 128; off > 0; off >>= 1) {
        if (t < off) red[t] += red[t + off];
        __syncthreads();
    }
    if (t == 0) bsum[b] = red[0];
}

__global__ __launch_bounds__(128) void scan_bsum(const int* __restrict__ bsum,
                                                 int* __restrict__ bbase, int nb) {
    __shared__ int sh[128];
    int t = threadIdx.x;
    sh[t] = (t < nb) ? bsum[t] : 0;
    __syncthreads();
    if (t == 0) {
        int run = 0;
        for (int i = 0; i < nb; ++i) { int v = sh[i]; sh[i] = run; run += v; }
    }
    __syncthreads();
    if (t < nb) bbase[t] = sh[t];
}

__global__ __launch_bounds__(256) void scan_write(const int* __restrict__ deg,
                                                  const int* __restrict__ bbase,
                                                  int* __restrict__ offs,
                                                  int* __restrict__ cursor) {
    __shared__ int red[256];
    int b = blockIdx.x, t = threadIdx.x;
    int base = b * 1024 + t * 4;
    int v[4];
    int s = 0;
#pragma unroll
    for (int j = 0; j < 4; ++j) {
        int i = base + j;
        v[j] = (i < NNODES) ? deg[i] : 0;
        s += v[j];
    }
    red[t] = s;
    __syncthreads();
    int x = s;
    for (int off = 1; off < 256; off <<= 1) {
        int y = (t >= off) ? red[t - off] : 0;
        __syncthreads();
        x += y;
        red[t] = x;
        __syncthreads();
    }
    int pre = bbase[b] + x - s;
#pragma unroll
    for (int j = 0; j < 4; ++j) {
        int i = base + j;
        if (i < NNODES) { offs[i] = pre; cursor[i] = pre; }
        pre += v[j];
    }
    if (b == gridDim.x - 1 && t == 255) offs[NNODES] = bbase[b] + x;
}

__global__ __launch_bounds__(256) void scatter_edges(const int* __restrict__ rows,
                                                     const int* __restrict__ cols,
                                                     int* __restrict__ cursor,
                                                     int* __restrict__ scol) {
    int i = blockIdx.x * 256 + threadIdx.x;
    if (i < NEDGES) {
        int p = atomicAdd(&cursor[rows[i]], 1);
        scol[p] = cols[i];
    }
}

// ---------------------------------------------------------------------------
// dtype conversion
// ---------------------------------------------------------------------------
__global__ __launch_bounds__(256) void convert_x_bf16(const float* __restrict__ src,
                                                      ushort* __restrict__ dst) {
    int i = blockIdx.x * 256 + threadIdx.x;
    const int n8 = NNODES * DFEAT / 8;
    if (i >= n8) return;
    float4 a = *(const float4*)&src[(size_t)i * 8];
    float4 b = *(const float4*)&src[(size_t)i * 8 + 4];
    ushort8v o;
    o[0] = f2bf(a.x); o[1] = f2bf(a.y); o[2] = f2bf(a.z); o[3] = f2bf(a.w);
    o[4] = f2bf(b.x); o[5] = f2bf(b.y); o[6] = f2bf(b.z); o[7] = f2bf(b.w);
    *(ushort8v*)&dst[(size_t)i * 8] = o;
}

__global__ __launch_bounds__(256) void convert_weights(const float* __restrict__ w0,
                                                       const float* __restrict__ w1,
                                                       const float* __restrict__ w2,
                                                       const float* __restrict__ w3,
                                                       const float* __restrict__ w4,
                                                       const float* __restrict__ w5,
                                                       ushort* __restrict__ dst) {
    int i = blockIdx.x * 256 + threadIdx.x;
    if (i >= 6 * DFEAT * DFEAT) return;
    const float* ptrs[6] = {w0, w1, w2, w3, w4, w5};
    int m = i >> 14, j = i & 16383;
    dst[i] = f2bf(ptrs[m][j]);
}

// ---------------------------------------------------------------------------
// Streaming GEMM, weights-in-registers: O = H @ W^T (bf16 in/out, f32 acc).
// gridDim.y selects (W1->S) / (W2->Y). Each wave holds all 32 weight
// fragments (128 VGPR) and grid-strides over 32-node tiles: per tile only
// 8 H-fragment loads + 64 MFMA + 16 stores. No LDS, no weight re-loads.
// ---------------------------------------------------------------------------
__global__ __launch_bounds__(256, 2) void gemm_stream(const ushort* __restrict__ Hb,
                                                      const ushort* __restrict__ W1b,
                                                      const ushort* __restrict__ W2b,
                                                      ushort* __restrict__ Sb,
                                                      ushort* __restrict__ Yb) {
    const ushort* __restrict__ W = blockIdx.y ? W2b : W1b;
    ushort* __restrict__ O = blockIdx.y ? Yb : Sb;
    int lane = threadIdx.x & 63;
    int l15 = lane & 15, lhi = lane >> 4;

    // load all weight fragments once: w[ot][ks] covers outs [ot*16, ot*16+16), k [ks*32, ks*32+32)
    bf16x8 w[8][4];
#pragma unroll
    for (int ot = 0; ot < 8; ++ot)
#pragma unroll
        for (int ks = 0; ks < 4; ++ks)
            w[ot][ks] = *(const bf16x8*)&W[(ot * 16 + l15) * DFEAT + ks * 32 + lhi * 8];

    int wid = blockIdx.x * 4 + (threadIdx.x >> 6);
    const int nwaves = gridDim.x * 4;
    const int ntiles = NNODES / 32;                 // 3125 exactly

    for (int t = wid; t < ntiles; t += nwaves) {
        int nodeBase = t * 32;
        bf16x8 hfr[2][4];
#pragma unroll
        for (int nt = 0; nt < 2; ++nt)
#pragma unroll
            for (int ks = 0; ks < 4; ++ks)
                hfr[nt][ks] = *(const bf16x8*)&Hb[(size_t)(nodeBase + nt * 16 + l15) * DFEAT +
                                                  ks * 32 + lhi * 8];
        f32x4 acc[2][8];
#pragma unroll
        for (int nt = 0; nt < 2; ++nt)
#pragma unroll
            for (int ot = 0; ot < 8; ++ot) {
                f32x4 a = {};
#pragma unroll
                for (int ks = 0; ks < 4; ++ks)
                    a = __builtin_amdgcn_mfma_f32_16x16x32_bf16(w[ot][ks], hfr[nt][ks], a, 0, 0, 0);
                acc[nt][ot] = a;
            }
#pragma unroll
        for (int nt = 0; nt < 2; ++nt) {
            size_t rowOff = (size_t)(nodeBase + nt * 16 + l15) * DFEAT;
#pragma unroll
            for (int ot = 0; ot < 8; ++ot) {
                f32x4 a = acc[nt][ot];
                ushort4 p;
                p.x = f2bf(a.x); p.y = f2bf(a.y); p.z = f2bf(a.z); p.w = f2bf(a.w);
                *(ushort4*)&O[rowOff + ot * 16 + lhi * 4] = p;
            }
        }
    }
}

// ---------------------------------------------------------------------------
// Aggregate + ReLU (bf16 in/out, f32 accumulate). One wave per node.
// ---------------------------------------------------------------------------
__global__ __launch_bounds__(256) void aggregate_relu_bf16(const ushort* __restrict__ Sb,
                                                           const ushort* __restrict__ Yb,
                                                           const int* __restrict__ offs,
                                                           const int* __restrict__ scol,
                                                           ushort* __restrict__ Hout) {
    int node = (blockIdx.x * 256 + threadIdx.x) >> 6;
    int lane = threadIdx.x & 63;
    if (node >= NNODES) return;
    int beg = offs[node];
    int end = offs[node + 1];
    const uint* Yp = (const uint*)Yb + lane;
    float ax = 0.f, ay = 0.f;
    int e = beg;
    for (; e + 3 < end; e += 4) {
        int c0 = scol[e], c1 = scol[e + 1], c2 = scol[e + 2], c3 = scol[e + 3];
        uint v0 = Yp[(size_t)c0 * 64];
        uint v1 = Yp[(size_t)c1 * 64];
        uint v2 = Yp[(size_t)c2 * 64];
        uint v3 = Yp[(size_t)c3 * 64];
        ax += (bflo2f(v0) + bflo2f(v1)) + (bflo2f(v2) + bflo2f(v3));
        ay += (bfhi2f(v0) + bfhi2f(v1)) + (bfhi2f(v2) + bfhi2f(v3));
    }
    for (; e < end; ++e) {
        uint v0 = Yp[(size_t)scol[e] * 64];
        ax += bflo2f(v0);
        ay += bfhi2f(v0);
    }
    uint sv = ((const uint*)Sb)[(size_t)node * 64 + lane];
    float hx = fmaxf(bflo2f(sv) + ax, 0.f);
    float hy = fmaxf(bfhi2f(sv) + ay, 0.f);
    uint packed = (uint)f2bf(hx) | ((uint)f2bf(hy) << 16);
    ((uint*)Hout)[(size_t)node * 64 + lane] = packed;
}

// ---------------------------------------------------------------------------
// Pooling phase 1: per-graph feature sums (run-accumulate over sorted batch).
// ---------------------------------------------------------------------------
__global__ __launch_bounds__(256) void pool_partial(const ushort* __restrict__ Hb,
                                                    const int* __restrict__ batch,
                                                    float* __restrict__ gsum) {
    int wave = (blockIdx.x * 256 + threadIdx.x) >> 6;
    int lane = threadIdx.x & 63;
    int base = wave * 64;
    if (base >= NNODES) return;
    int end = min(base + 64, NNODES);
    const uint* Hp = (const uint*)Hb + lane;
    float ax = 0.f, ay = 0.f;
    int gprev = batch[base];
    for (int n = base; n < end; ++n) {
        int g = batch[n];
        if (g != gprev) {
            atomicAdd(&gsum[gprev * DFEAT + lane * 2], ax);
            atomicAdd(&gsum[gprev * DFEAT + lane * 2 + 1], ay);
            ax = 0.f; ay = 0.f; gprev = g;
        }
        uint v = Hp[(size_t)n * 64];
        ax += bflo2f(v);
        ay += bfhi2f(v);
    }
    atomicAdd(&gsum[gprev * DFEAT + lane * 2], ax);
    atomicAdd(&gsum[gprev * DFEAT + lane * 2 + 1], ay);
}

// ---------------------------------------------------------------------------
// Pooling phase 2: divide by count, classify.
// ---------------------------------------------------------------------------
__global__ __launch_bounds__(128) void pool_classify2(const float* __restrict__ gsum,
                                                      const int* __restrict__ batch,
                                                      const float* __restrict__ Wc,
                                                      const float* __restrict__ bc,
                                                      float* __restrict__ out) {
    int g = blockIdx.x;
    int f = threadIdx.x;
    __shared__ int bounds[2];
    if (f < 2) {
        int target = g + f;
        int lo = 0, hi = NNODES;
        while (lo < hi) {
            int mid = (lo + hi) >> 1;
            if (batch[mid] < target) lo = mid + 1; else hi = mid;
        }
        bounds[f] = lo;
    }
    __syncthreads();
    float cnt = (float)(bounds[1] - bounds[0]);
    float pooled = gsum[g * DFEAT + f] / fmaxf(cnt, 1.0f);

    __shared__ float red[128];
    for (int o = 0; o < DOUTC; ++o) {
        red[f] = pooled * Wc[o * DFEAT + f];
        __syncthreads();
        for (int off = 64; off > 0; off >>= 1) {
            if (f < off) red[f] += red[f + off];
            __syncthreads();
        }
        if (f == 0) out[g * DOUTC + o] = red[0] + bc[o];
        __syncthreads();
    }
}

// ---------------------------------------------------------------------------
extern "C" void kernel_launch(void* const* d_in, const int* in_sizes, int n_in,
                              void* d_out, int out_size, void* d_ws, size_t ws_size,
                              hipStream_t stream) {
    const float* x    = (const float*)d_in[0];
    const int*   ei   = (const int*)d_in[1];
    const int*   batch= (const int*)d_in[2];
    const float* W1_0 = (const float*)d_in[3];
    const float* W2_0 = (const float*)d_in[4];
    const float* W1_1 = (const float*)d_in[5];
    const float* W2_1 = (const float*)d_in[6];
    const float* W1_2 = (const float*)d_in[7];
    const float* W2_2 = (const float*)d_in[8];
    const float* Wc   = (const float*)d_in[9];
    const float* bc   = (const float*)d_in[10];
    float* out = (float*)d_out;

    const int* rows = ei;            // edge_index[0] = dst (segment)
    const int* cols = ei + NEDGES;   // edge_index[1] = src (gather)

    // workspace carve-up
    char* ws = (char*)d_ws;
    ushort* Hb = (ushort*)ws;  ws += (size_t)NNODES * DFEAT * sizeof(ushort);
    ushort* Sb = (ushort*)ws;  ws += (size_t)NNODES * DFEAT * sizeof(ushort);
    ushort* Yb = (ushort*)ws;  ws += (size_t)NNODES * DFEAT * sizeof(ushort);
    ushort* Wb = (ushort*)ws;  ws += (size_t)6 * DFEAT * DFEAT * sizeof(ushort);
    float* gsum = (float*)ws;  ws += (size_t)NGRAPH * DFEAT * sizeof(float);
    int* deg    = (int*)ws;    ws += (size_t)NNODES * sizeof(int);
    int* offs   = (int*)ws;    ws += (size_t)(NNODES + 1) * sizeof(int);
    int* cursor = (int*)ws;    ws += (size_t)NNODES * sizeof(int);
    int* scol   = (int*)ws;    ws += (size_t)NEDGES * sizeof(int);
    int* bsum   = (int*)ws;    ws += 128 * sizeof(int);
    int* bbase  = (int*)ws;    ws += 128 * sizeof(int);

    const int NB = (NNODES + 1023) / 1024;

    // dtype conversion
    convert_weights<<<(6 * DFEAT * DFEAT + 255) / 256, 256, 0, stream>>>(
        W1_0, W2_0, W1_1, W2_1, W1_2, W2_2, Wb);
    convert_x_bf16<<<(NNODES * DFEAT / 8 + 255) / 256, 256, 0, stream>>>(x, Hb);

    // CSR build
    hipMemsetAsync(deg, 0, (size_t)NNODES * sizeof(int), stream);
    hipMemsetAsync(gsum, 0, (size_t)NGRAPH * DFEAT * sizeof(float), stream);
    histo_kernel<<<(NEDGES + 255) / 256, 256, 0, stream>>>(rows, deg);
    scan_block_sums<<<NB, 256, 0, stream>>>(deg, bsum);
    scan_bsum<<<1, 128, 0, stream>>>(bsum, bbase, NB);
    scan_write<<<NB, 256, 0, stream>>>(deg, bbase, offs, cursor);
    scatter_edges<<<(NEDGES + 255) / 256, 256, 0, stream>>>(rows, cols, cursor, scol);

    // 3 GNN layers
    const dim3 gemmGrid(392, 2);                     // y=0: W1->S, y=1: W2->Y
    const int aggGrid  = ((size_t)NNODES * 64 + 255) / 256;
    for (int l = 0; l < 3; ++l) {
        const ushort* w1 = Wb + (size_t)(2 * l) * DFEAT * DFEAT;
        const ushort* w2 = Wb + (size_t)(2 * l + 1) * DFEAT * DFEAT;
        gemm_stream<<<gemmGrid, 256, 0, stream>>>(Hb, w1, w2, Sb, Yb);
        aggregate_relu_bf16<<<aggGrid, 256, 0, stream>>>(Sb, Yb, offs, scol, Hb);
    }

    // pooling + classifier
    const int poolWaves = (NNODES + 63) / 64;
    pool_partial<<<(poolWaves * 64 + 255) / 256, 256, 0, stream>>>(Hb, batch, gsum);
    pool_classify2<<<NGRAPH, 128, 0, stream>>>(gsum, batch, Wc, bc, out);
}